// Round 7
// baseline (2105.979 us; speedup 1.0000x reference)
//
#include <hip/hip_runtime.h>
#include <math.h>

#define PSTR 40     // LDS fp16 patch row stride: 80 B (2-way bank aliasing = free)

typedef _Float16 half8 __attribute__((ext_vector_type(8)));
typedef float    f32x4 __attribute__((ext_vector_type(4)));

__device__ __forceinline__ float fast_tanh(float v) {
    float e = __expf(2.f * v);
    return 1.f - 2.f / (e + 1.f);
}
__device__ __forceinline__ float hsig(float v) {
    return fminf(fmaxf(0.2f * v + 0.5f, 0.f), 1.f);
}

// Pack: Wcx[tap][n][ci<32] from Wx[tap][ci][n]; Wch[tap][n][ci] from Wh[tap][ci][n]
__global__ void prep_w(const float* __restrict__ Wx, const float* __restrict__ Wh,
                       _Float16* __restrict__ Wcx, _Float16* __restrict__ Wch) {
    const int k = blockIdx.x, n = threadIdx.x;
    const int tap = k >> 6, ci = k & 63;
    if (ci < 32) Wcx[(tap * 128 + n) * 32 + ci]        = (_Float16)Wx[(tap * 32 + ci) * 128 + n];
    else         Wch[(tap * 128 + n) * 32 + (ci - 32)] = (_Float16)Wh[(tap * 32 + (ci - 32)) * 128 + n];
}

// Persistent cooperative kernel: 256 blocks (1/CU) x 512 threads (8 waves).
// Block: 8x16 px tile of one batch image. Wave (chg=w&1, mtg=w>>1): rows {2mtg,2mtg+1}
// x 64 ch; ch = nt*32 + chg*16 + l15 -> nt = gate index, f = chg*16+l15.
// Phase 1: xg = conv(x,Wx)+bias for all t (weights in VGPRs, no cross-block dep).
// Phase 2: per-t h-conv + LSTM; c in registers; h via 17 global buffers; neighbor
// flag sync (device-scope atomics + threadfence) instead of 40us grid.sync.
__global__ __launch_bounds__(512, 2)
void convlstm_persist(const float* __restrict__ x,
                      const _Float16* __restrict__ Wcx,
                      const _Float16* __restrict__ Wch,
                      const float* __restrict__ bias,
                      const float* __restrict__ gamma_,
                      const float* __restrict__ beta_,
                      const float* __restrict__ mmean,
                      const float* __restrict__ mvar,
                      _Float16* __restrict__ hbufs,   // 17 x 1,048,576 fp16 (slot0 zeroed)
                      int* __restrict__ flags,        // [17][256] (zeroed)
                      _Float16* __restrict__ xg,      // [256][16][512][32] fp16
                      float* __restrict__ out)        // [B,T,H,W,32] fp32
{
    __shared__ _Float16 patch[180 * PSTR];   // 14.4 KB: 10x18 halo x 32 ch

    const int tid  = threadIdx.x;
    const int lane = tid & 63;
    const int wv   = tid >> 6;
    const int l15  = lane & 15, quad = lane >> 4;
    const int chg  = wv & 1, mtg = wv >> 1;          // mtg 0..3
    const int blk  = blockIdx.x;
    const int b    = blk >> 5, tile = blk & 31;
    const int ty   = tile >> 2, tx = tile & 3;
    const int py0  = ty * 8, px0 = tx * 16;
    const int f    = chg * 16 + l15;

    // 8-connected neighbor block ids (clipped -> self, whose flag is always set in time)
    int nb[8];
    {
        int j = 0;
        #pragma unroll
        for (int dy = -1; dy <= 1; ++dy)
            #pragma unroll
            for (int dx = -1; dx <= 1; ++dx) {
                if (dy == 0 && dx == 0) continue;
                const int ny = ty + dy, nx = tx + dx;
                nb[j++] = ((unsigned)ny < 8u && (unsigned)nx < 4u) ? (b * 32 + ny * 4 + nx) : blk;
            }
    }

    // ---- weight fragments in registers (36 x 16 B = 144 VGPRs) ----
    half8 wf[9][4];
    #pragma unroll
    for (int tap = 0; tap < 9; ++tap)
        #pragma unroll
        for (int nt = 0; nt < 4; ++nt)
            wf[tap][nt] = *(const half8*)(Wcx + ((tap * 128 + nt * 32 + f) * 32 + quad * 8));

    float bi[4];
    #pragma unroll
    for (int nt = 0; nt < 4; ++nt) bi[nt] = bias[nt * 32 + f];

    // ======== Phase 1: xg[t] = conv(x_t, Wx) + bias, lane-layout fp16 ========
    for (int t = 0; t < 16; ++t) {
        const float* xt = x + (((size_t)b * 16 + t) * 4096) * 32;
        for (int i = tid; i < 720; i += 512) {
            const int pos = i >> 2, q = i & 3;
            const int row = pos / 18, col = pos - row * 18;
            const int gy = py0 + row - 1, gx = px0 + col - 1;
            half8 hv = {0, 0, 0, 0, 0, 0, 0, 0};
            if ((unsigned)gy < 64u && (unsigned)gx < 64u) {
                const float* s = xt + ((size_t)(gy * 64 + gx)) * 32 + q * 8;
                const float4 v0 = *(const float4*)s;
                const float4 v1 = *(const float4*)(s + 4);
                hv = (half8){(_Float16)v0.x, (_Float16)v0.y, (_Float16)v0.z, (_Float16)v0.w,
                             (_Float16)v1.x, (_Float16)v1.y, (_Float16)v1.z, (_Float16)v1.w};
            }
            *(half8*)&patch[pos * PSTR + q * 8] = hv;
        }
        __syncthreads();

        f32x4 acc[2][4];
        #pragma unroll
        for (int mt = 0; mt < 2; ++mt)
            #pragma unroll
            for (int nt = 0; nt < 4; ++nt)
                acc[mt][nt] = (f32x4){bi[nt], bi[nt], bi[nt], bi[nt]};

        #pragma unroll
        for (int tap = 0; tap < 9; ++tap) {
            const int ky = tap / 3, kx = tap - ky * 3;
            const half8 a0 = *(const half8*)&patch[((mtg * 2 + 0 + ky) * 18 + l15 + kx) * PSTR + quad * 8];
            const half8 a1 = *(const half8*)&patch[((mtg * 2 + 1 + ky) * 18 + l15 + kx) * PSTR + quad * 8];
            #pragma unroll
            for (int nt = 0; nt < 4; ++nt) {
                acc[0][nt] = __builtin_amdgcn_mfma_f32_16x16x32_f16(a0, wf[tap][nt], acc[0][nt], 0, 0, 0);
                acc[1][nt] = __builtin_amdgcn_mfma_f32_16x16x32_f16(a1, wf[tap][nt], acc[1][nt], 0, 0, 0);
            }
        }

        half8 hv4[4];
        #pragma unroll
        for (int mt = 0; mt < 2; ++mt)
            #pragma unroll
            for (int nt = 0; nt < 4; ++nt)
                #pragma unroll
                for (int r = 0; r < 4; ++r)
                    hv4[mt * 2 + (nt >> 1)][(nt & 1) * 4 + r] = (_Float16)acc[mt][nt][r];
        _Float16* dst = xg + ((size_t)(blk * 16 + t) * 512 + tid) * 32;
        #pragma unroll
        for (int j = 0; j < 4; ++j) *(half8*)(dst + j * 8) = hv4[j];
        __syncthreads();
    }

    // ---- swap Wh into the same registers ----
    #pragma unroll
    for (int tap = 0; tap < 9; ++tap)
        #pragma unroll
        for (int nt = 0; nt < 4; ++nt)
            wf[tap][nt] = *(const half8*)(Wch + ((tap * 128 + nt * 32 + f) * 32 + quad * 8));

    const float inv = gamma_[f] * rsqrtf(mvar[f] + 1e-3f);
    const float bnb = beta_[f] - mmean[f] * inv;
    float creg[2][4] = {{0.f, 0.f, 0.f, 0.f}, {0.f, 0.f, 0.f, 0.f}};

    // ======== Phase 2: sequential steps with neighbor-flag sync ========
    for (int t = 0; t < 16; ++t) {
        if (t > 0) {
            if (tid < 8) {
                int* p = &flags[t * 256 + nb[tid]];
                while (__hip_atomic_load(p, __ATOMIC_RELAXED, __HIP_MEMORY_SCOPE_AGENT) == 0)
                    __builtin_amdgcn_s_sleep(2);
            }
            __syncthreads();
            __threadfence();   // acquire: invalidate stale h lines before reading
        }

        // stage h patch from slot t
        const _Float16* hbt = hbufs + (size_t)t * 1048576 + (size_t)b * 131072;
        for (int i = tid; i < 720; i += 512) {
            const int pos = i >> 2, q = i & 3;
            const int row = pos / 18, col = pos - row * 18;
            const int gy = py0 + row - 1, gx = px0 + col - 1;
            half8 hv = {0, 0, 0, 0, 0, 0, 0, 0};
            if ((unsigned)gy < 64u && (unsigned)gx < 64u)
                hv = *(const half8*)(hbt + ((size_t)(gy * 64 + gx)) * 32 + q * 8);
            *(half8*)&patch[pos * PSTR + q * 8] = hv;
        }
        __syncthreads();

        f32x4 acc[2][4];
        #pragma unroll
        for (int mt = 0; mt < 2; ++mt)
            #pragma unroll
            for (int nt = 0; nt < 4; ++nt)
                acc[mt][nt] = (f32x4){0.f, 0.f, 0.f, 0.f};

        #pragma unroll
        for (int tap = 0; tap < 9; ++tap) {
            const int ky = tap / 3, kx = tap - ky * 3;
            const half8 a0 = *(const half8*)&patch[((mtg * 2 + 0 + ky) * 18 + l15 + kx) * PSTR + quad * 8];
            const half8 a1 = *(const half8*)&patch[((mtg * 2 + 1 + ky) * 18 + l15 + kx) * PSTR + quad * 8];
            #pragma unroll
            for (int nt = 0; nt < 4; ++nt) {
                acc[0][nt] = __builtin_amdgcn_mfma_f32_16x16x32_f16(a0, wf[tap][nt], acc[0][nt], 0, 0, 0);
                acc[1][nt] = __builtin_amdgcn_mfma_f32_16x16x32_f16(a1, wf[tap][nt], acc[1][nt], 0, 0, 0);
            }
        }

        // ---- epilogue: gates = acc + xg; LSTM with register c; BN ----
        const _Float16* xgp = xg + ((size_t)(blk * 16 + t) * 512 + tid) * 32;
        half8 xv[4];
        #pragma unroll
        for (int j = 0; j < 4; ++j) xv[j] = *(const half8*)(xgp + j * 8);

        _Float16* hq = hbufs + (size_t)(t + 1) * 1048576 + (size_t)b * 131072;
        float* oq = out + (((size_t)b * 16 + t) * 4096) * 32;

        #pragma unroll
        for (int mt = 0; mt < 2; ++mt) {
            #pragma unroll
            for (int r = 0; r < 4; ++r) {
                const int gy = py0 + mtg * 2 + mt;
                const int gx = px0 + quad * 4 + r;
                const float gi = acc[mt][0][r] + (float)xv[mt * 2 + 0][0 + r];
                const float gf = acc[mt][1][r] + (float)xv[mt * 2 + 0][4 + r];
                const float gc = acc[mt][2][r] + (float)xv[mt * 2 + 1][0 + r];
                const float go = acc[mt][3][r] + (float)xv[mt * 2 + 1][4 + r];
                const float cn = hsig(gf) * creg[mt][r] + hsig(gi) * fast_tanh(gc);
                const float hv = hsig(go) * fast_tanh(cn);
                creg[mt][r] = cn;
                const size_t pix = ((size_t)(gy * 64 + gx)) * 32 + f;
                hq[pix] = (_Float16)hv;
                oq[pix] = hv * inv + bnb;
            }
        }

        __threadfence();   // release: h writes visible device-wide
        __syncthreads();   // all threads' writes+fences done before flag
        if (tid == 0)
            __hip_atomic_store(&flags[(t + 1) * 256 + blk], 1,
                               __ATOMIC_RELEASE, __HIP_MEMORY_SCOPE_AGENT);
    }
}

extern "C" void kernel_launch(void* const* d_in, const int* in_sizes, int n_in,
                              void* d_out, int out_size, void* d_ws, size_t ws_size,
                              hipStream_t stream)
{
    const float* x      = (const float*)d_in[0];
    const float* Wx     = (const float*)d_in[1];
    const float* Wh     = (const float*)d_in[2];
    const float* bias   = (const float*)d_in[3];
    const float* gamma_ = (const float*)d_in[4];
    const float* beta_  = (const float*)d_in[5];
    const float* mmean  = (const float*)d_in[6];
    const float* mvar   = (const float*)d_in[7];
    float* out = (float*)d_out;

    // ws layout (bytes):
    //   hbufs  @ 0          : 17 x 2 MiB = 35,651,584
    //   flags  @ 35,651,584 : 64 KiB
    //   Wcx    @ 35,717,120 : 73,728
    //   Wch    @ 35,790,848 : 73,728
    //   xg     @ 35,864,576 : 134,217,728  (end ~170 MB)
    char* wsb = (char*)d_ws;
    _Float16* hbufs = (_Float16*)wsb;
    int*      flags = (int*)(wsb + 35651584);
    _Float16* Wcx   = (_Float16*)(wsb + 35717120);
    _Float16* Wch   = (_Float16*)(wsb + 35790848);
    _Float16* xg    = (_Float16*)(wsb + 35864576);

    hipMemsetAsync(wsb, 0, 2097152, stream);            // h slot 0 = zeros
    hipMemsetAsync(wsb + 35651584, 0, 65536, stream);   // flags = 0
    prep_w<<<dim3(576), dim3(128), 0, stream>>>(Wx, Wh, Wcx, Wch);

    void* args[] = {(void*)&x, (void*)&Wcx, (void*)&Wch, (void*)&bias, (void*)&gamma_,
                    (void*)&beta_, (void*)&mmean, (void*)&mvar,
                    (void*)&hbufs, (void*)&flags, (void*)&xg, (void*)&out};
    hipLaunchCooperativeKernel((void*)convlstm_persist, dim3(256), dim3(512), args, 0, stream);
}